// Round 4
// baseline (7882.340 us; speedup 1.0000x reference)
//
#include <hip/hip_runtime.h>
#include <cstddef>

#define U_DIM 512
#define T_DIM 2048
#define B_DIM 32
#define F_DIM 1024
#define M_DIM (B_DIM * T_DIM)
#define NBLK 8               // blocks per batch
#define UB (U_DIM / NBLK)    // 64 u-states per block
#define NFLAG 64             // per-wave flags per batch = NBLK * 8 waves

#define AT_LOAD(p)  __hip_atomic_load((p), __ATOMIC_RELAXED, __HIP_MEMORY_SCOPE_AGENT)
#define AT_STORE(p, v) __hip_atomic_store((p), (v), __ATOMIC_RELAXED, __HIP_MEMORY_SCOPE_AGENT)

// ---------------------------------------------------------------------------
// GEMM: potentials[m][n] = sum_k x[m][k]*W[k][n] + b[n] (+ boundary at t=0/T-1)
// fp32 vector-ALU (no fp32 MFMA on CDNA4). 128x64 tile, 256 threads, 8x4 micro.
// (unchanged — known good, ~0.9 ms)
// ---------------------------------------------------------------------------
#define BM 128
#define BN 64
#define BK 16

__global__ __launch_bounds__(256) void gemm_kernel(
    const float* __restrict__ x, const float* __restrict__ W,
    const float* __restrict__ bias, const float* __restrict__ lb,
    const float* __restrict__ rb, float* __restrict__ out)
{
  __shared__ float As[BK][BM + 4];
  __shared__ float Bs[BK][BN];
  const int m0 = blockIdx.x * BM;
  const int n0 = blockIdx.y * BN;
  const int tid = threadIdx.x;
  const int tx = tid & 15;
  const int ty = tid >> 4;

  float acc[8][4];
#pragma unroll
  for (int i = 0; i < 8; ++i)
#pragma unroll
    for (int j = 0; j < 4; ++j) acc[i][j] = 0.f;

  for (int k0 = 0; k0 < F_DIM; k0 += BK) {
#pragma unroll
    for (int i = 0; i < 2; ++i) {
      int id = i * 256 + tid;
      int row = id >> 2;
      int c4 = (id & 3) << 2;
      float4 a = *(const float4*)(x + (size_t)(m0 + row) * F_DIM + k0 + c4);
      As[c4 + 0][row] = a.x;
      As[c4 + 1][row] = a.y;
      As[c4 + 2][row] = a.z;
      As[c4 + 3][row] = a.w;
    }
    {
      int krow = tid >> 4;
      int c4 = (tid & 15) << 2;
      *(float4*)(&Bs[krow][c4]) =
          *(const float4*)(W + (size_t)(k0 + krow) * U_DIM + n0 + c4);
    }
    __syncthreads();
#pragma unroll
    for (int k = 0; k < BK; ++k) {
      float a[8], bb[4];
#pragma unroll
      for (int i = 0; i < 8; ++i) a[i] = As[k][ty * 8 + i];
#pragma unroll
      for (int j = 0; j < 4; ++j) bb[j] = Bs[k][tx * 4 + j];
#pragma unroll
      for (int i = 0; i < 8; ++i)
#pragma unroll
        for (int j = 0; j < 4; ++j) acc[i][j] += a[i] * bb[j];
    }
    __syncthreads();
  }

#pragma unroll
  for (int i = 0; i < 8; ++i) {
    int m = m0 + ty * 8 + i;
    int t = m & (T_DIM - 1);
    float4 o;
#pragma unroll
    for (int j = 0; j < 4; ++j) {
      int n = n0 + tx * 4 + j;
      float v = acc[i][j] + bias[n];
      if (t == 0) v += lb[n];
      if (t == T_DIM - 1) v += rb[n];
      ((float*)&o)[j] = v;
    }
    *(float4*)(out + (size_t)m * U_DIM + n0 + tx * 4) = o;
  }
}

// ---------------------------------------------------------------------------
// aux: copy transitions to output tail, build transposed TrT[u][v] in ws,
// write sequence_lengths.
// ---------------------------------------------------------------------------
__global__ void aux_kernel(const float* __restrict__ tr, float* __restrict__ out_tr,
                           float* __restrict__ trT, float* __restrict__ seqlen)
{
  int idx = blockIdx.x * blockDim.x + threadIdx.x;
  if (idx < U_DIM * U_DIM) {
    float v = tr[idx];
    out_tr[idx] = v;
    int r = idx >> 9;   // v
    int c = idx & 511;  // u
    trT[(size_t)c * U_DIM + r] = v;
  }
  if (idx < B_DIM) seqlen[idx] = (float)T_DIM;
}

// zero the per-wave flags and per-block done words (ws is poisoned)
__global__ void init_kernel(unsigned int* __restrict__ flags,
                            unsigned int* __restrict__ done)
{
  int i = blockIdx.x * blockDim.x + threadIdx.x;
  if (i < B_DIM * NFLAG) flags[i] = 0u;
  if (i < B_DIM * NBLK) done[i] = 0u;
}

// ---------------------------------------------------------------------------
// Viterbi forward scan, full-chip: 256 blocks = 8 u-slice blocks x 32 batches.
// blockIdx: b = blk & 31, j = blk >> 5 (u-slice).
// 512 threads: u_local = tid>>3 (64 u's), vseg = tid&7.
// trT slice held in 16 float4 regs per thread (loaded once).
//
// Sync protocol v4 — per-WAVE flags, flag/word pairing, ONE barrier/step:
//  * wave w of block j produces state words u = j*64 + w*8 .. +7 and owns
//    flag[b][j*8+w]. Producer order (in-wave): state sc1 stores ->
//    s_waitcnt vmcnt(0) (own-store ack only; no block barrier, no cross-wave
//    skew) -> flag store = t -> bp nt store (off the critical drain).
//  * consumer thread tid needs exactly state word tid, guarded by
//    flag[tid>>3] (8 threads broadcast-poll one 4B word -> one cacheline per
//    polling wave per iteration, vs R3's 4-8 lines of u64s). After ITS poll
//    succeeds, ITS sc1 word load is safe -> no barrier between poll & load.
//  * single __syncthreads per step (LDS write -> compute).
//  * phase alignment: a wave passes poll(t) only after ALL waves of its own
//    block published t (they publish only after barrier(t)) -> no wave can
//    be more than one barrier ahead; sh_state double-buffered.
//  * WAR: any flag(t-1) implies its whole block passed barrier(t-1), i.e.
//    consumed state(t-2) -> overwriting slot t&1 at step t is safe.
//  * bp visibility: ONE agent-release fence per block after the loop, then
//    done-flag; backtracker polls done, acquire-fences, reads bp cached.
// ---------------------------------------------------------------------------
__global__ __launch_bounds__(512) void scan_kernel(
    const float* __restrict__ pot, const float* __restrict__ trT,
    float* __restrict__ stateBuf,        // [2][B][U]
    unsigned int* __restrict__ flags,    // [B][NFLAG] per-wave step numbers
    unsigned int* __restrict__ done,     // [B][NBLK]
    unsigned short* __restrict__ bp,     // [T-1][B][U]
    float* __restrict__ outv)            // [B][T]
{
  const int blk = blockIdx.x;
  const int b = blk & (B_DIM - 1);
  const int j = blk >> 5;
  const int tid = threadIdx.x;
  const int u_local = tid >> 3;
  const int vseg = tid & 7;
  const int u = j * UB + u_local;
  const int wave = tid >> 6;

  __shared__ float sh_state[2][U_DIM];
  __shared__ float sh_v[U_DIM];
  __shared__ int sh_i[U_DIM];

  // load this thread's transition slice into registers (once)
  float4 trreg[16];
  const float* trRow = trT + (size_t)u * U_DIM;
#pragma unroll
  for (int m = 0; m < 16; ++m)
    trreg[m] = *(const float4*)(trRow + vseg * 4 + m * 32);

  const float* potb = pot + (size_t)b * T_DIM * U_DIM;
  unsigned int* bflags = flags + b * NFLAG;

  for (int t = 1; t < T_DIM; ++t) {
    const int cur = t & 1;
    // independent of peers: issue before the wait so latency hides under it
    float p_u = potb[(size_t)t * U_DIM + u];  // 8-lane broadcast

    if (t > 1) {
      const unsigned int want = (unsigned int)(t - 1);
      // poll exactly the flag guarding MY state word
      while (AT_LOAD(&bflags[tid >> 3]) < want) {}
      // my word is now valid at the coherence point
      sh_state[cur][tid] = AT_LOAD(
          &stateBuf[(size_t)((t - 1) & 1) * B_DIM * U_DIM +
                    (size_t)b * U_DIM + tid]);
    } else {
      // t==1: state0 = potentials[:,0] (written by gemm kernel, same stream)
      sh_state[cur][tid] = potb[tid];
    }
    __syncthreads();  // the only barrier per step

    float best = -3.402823466e38f;
    int bi = 0;
#pragma unroll
    for (int m = 0; m < 16; ++m) {
      float4 st = *(const float4*)(&sh_state[cur][vseg * 4 + m * 32]);
      float4 trv = trreg[m];
      int vbase = vseg * 4 + m * 32;
      float s0 = st.x + trv.x;
      float s1 = st.y + trv.y;
      float s2 = st.z + trv.z;
      float s3 = st.w + trv.w;
      if (s0 > best) { best = s0; bi = vbase; }
      if (s1 > best) { best = s1; bi = vbase + 1; }
      if (s2 > best) { best = s2; bi = vbase + 2; }
      if (s3 > best) { best = s3; bi = vbase + 3; }
    }
    // combine the 8 vseg partials (lanes u_local*8 .. +7), first-max tie rule
#pragma unroll
    for (int d = 1; d < 8; d <<= 1) {
      float ob = __shfl_xor(best, d, 64);
      int oi = __shfl_xor(bi, d, 64);
      if (ob > best || (ob == best && oi < bi)) { best = ob; bi = oi; }
    }
    float ns = best + p_u;
    if (vseg == 0) {
      AT_STORE(&stateBuf[(size_t)cur * B_DIM * U_DIM + (size_t)b * U_DIM + u],
               ns);
    }
    // wait own wave's state stores acked at the coherence point, then
    // publish this wave's flag; bp store issued AFTER (off the drain path)
    asm volatile("s_waitcnt vmcnt(0)" ::: "memory");
    if ((tid & 63) == 0)
      AT_STORE(&bflags[j * 8 + wave], (unsigned int)t);
    if (vseg == 0)
      __builtin_nontemporal_store(
          (unsigned short)bi,
          &bp[(size_t)(t - 1) * (B_DIM * U_DIM) + (size_t)b * U_DIM + u]);
  }

  // One release fence per block (single wbl2): makes the nt bp stores
  // visible device-wide, then publish "done".
  __syncthreads();  // drains all waves' bp stores (vmcnt(0) at barrier)
  if (tid == 0) {
    __builtin_amdgcn_fence(__ATOMIC_RELEASE, "agent");
    AT_STORE(&done[b * NBLK + j], 1u);
  }

  // block j==0 of each batch: final argmax + backtrack
  if (j == 0) {
    if (tid < NBLK) {
      while (AT_LOAD(&done[b * NBLK + tid]) == 0u) {}
    }
    __syncthreads();
    // one acquire fence: invalidate possibly-stale L1/L2 lines (bp was
    // written by remote blocks; ws poison from previous launch may linger)
    if (tid == 0) __builtin_amdgcn_fence(__ATOMIC_ACQUIRE, "agent");
    __syncthreads();

    {
      float w = AT_LOAD(&stateBuf[(size_t)1 * B_DIM * U_DIM +
                                  (size_t)b * U_DIM + tid]);
      sh_v[tid] = w;
      sh_i[tid] = tid;
    }
    __syncthreads();
    for (int s = 256; s > 0; s >>= 1) {
      if (tid < s) {
        float a = sh_v[tid], c = sh_v[tid + s];
        int ia = sh_i[tid], ic = sh_i[tid + s];
        if (c > a || (c == a && ic < ia)) { sh_v[tid] = c; sh_i[tid] = ic; }
      }
      __syncthreads();
    }
    if (tid == 0) {
      int tag = sh_i[0];
      outv[(size_t)b * T_DIM + (T_DIM - 1)] = (float)tag;
      for (int t = T_DIM - 1; t >= 1; --t) {
        tag = bp[(size_t)(t - 1) * (B_DIM * U_DIM) + (size_t)b * U_DIM + tag];
        outv[(size_t)b * T_DIM + (t - 1)] = (float)tag;
      }
    }
  }
}

// ---------------------------------------------------------------------------
extern "C" void kernel_launch(void* const* d_in, const int* in_sizes, int n_in,
                              void* d_out, int out_size, void* d_ws, size_t ws_size,
                              hipStream_t stream)
{
  const float* x    = (const float*)d_in[0];
  const float* W    = (const float*)d_in[1];
  const float* bias = (const float*)d_in[2];
  const float* tr   = (const float*)d_in[3];
  const float* lb   = (const float*)d_in[4];
  const float* rb   = (const float*)d_in[5];

  float* out = (float*)d_out;
  float* out_v   = out;                                      // (B,T) viterbi tags
  float* out_pot = out + (size_t)B_DIM * T_DIM;              // (B,T,U) potentials
  float* out_seq = out_pot + (size_t)B_DIM * T_DIM * U_DIM;  // (B,) seq lengths
  float* out_tr  = out_seq + B_DIM;                          // (U,U) transitions

  // ws layout
  float* trT = (float*)d_ws;                                           // 1 MB
  float* stateBuf = trT + (size_t)U_DIM * U_DIM;                       // 128 KB
  unsigned int* flags = (unsigned int*)(stateBuf + 2 * B_DIM * U_DIM); // 8 KB
  unsigned int* done  = flags + B_DIM * NFLAG;                         // 1 KB
  unsigned short* bp  = (unsigned short*)(done + B_DIM * NBLK);        // ~64 MB

  hipLaunchKernelGGL(init_kernel, dim3(8), dim3(256), 0, stream, flags, done);
  hipLaunchKernelGGL(aux_kernel, dim3(1024), dim3(256), 0, stream,
                     tr, out_tr, trT, out_seq);
  hipLaunchKernelGGL(gemm_kernel, dim3(M_DIM / BM, U_DIM / BN), dim3(256), 0,
                     stream, x, W, bias, lb, rb, out_pot);
  hipLaunchKernelGGL(scan_kernel, dim3(NBLK * B_DIM), dim3(512), 0, stream,
                     out_pot, trT, stateBuf, flags, done, bp, out_v);
}

// Round 5
// 6282.066 us; speedup vs baseline: 1.2547x; 1.2547x over previous
//
#include <hip/hip_runtime.h>
#include <cstddef>

#define U_DIM 512
#define T_DIM 2048
#define B_DIM 32
#define F_DIM 1024
#define M_DIM (B_DIM * T_DIM)
#define NBLK 8               // blocks per batch
#define UB (U_DIM / NBLK)    // 64 u-states per block
#define RING 8               // state ring slots (>= 5 needed; 8 for cheap mod)
#define SENT 0xFF800001u     // NaN payload: never produced by finite max/add

#define AT_LOAD(p)  __hip_atomic_load((p), __ATOMIC_RELAXED, __HIP_MEMORY_SCOPE_AGENT)
#define AT_STORE(p, v) __hip_atomic_store((p), (v), __ATOMIC_RELAXED, __HIP_MEMORY_SCOPE_AGENT)

// ---------------------------------------------------------------------------
// GEMM: potentials[m][n] = sum_k x[m][k]*W[k][n] + b[n] (+ boundary at t=0/T-1)
// fp32 vector-ALU (no fp32 MFMA on CDNA4). 128x64 tile, 256 threads, 8x4 micro.
// (unchanged — known good, ~0.9 ms)
// ---------------------------------------------------------------------------
#define BM 128
#define BN 64
#define BK 16

__global__ __launch_bounds__(256) void gemm_kernel(
    const float* __restrict__ x, const float* __restrict__ W,
    const float* __restrict__ bias, const float* __restrict__ lb,
    const float* __restrict__ rb, float* __restrict__ out)
{
  __shared__ float As[BK][BM + 4];
  __shared__ float Bs[BK][BN];
  const int m0 = blockIdx.x * BM;
  const int n0 = blockIdx.y * BN;
  const int tid = threadIdx.x;
  const int tx = tid & 15;
  const int ty = tid >> 4;

  float acc[8][4];
#pragma unroll
  for (int i = 0; i < 8; ++i)
#pragma unroll
    for (int j = 0; j < 4; ++j) acc[i][j] = 0.f;

  for (int k0 = 0; k0 < F_DIM; k0 += BK) {
#pragma unroll
    for (int i = 0; i < 2; ++i) {
      int id = i * 256 + tid;
      int row = id >> 2;
      int c4 = (id & 3) << 2;
      float4 a = *(const float4*)(x + (size_t)(m0 + row) * F_DIM + k0 + c4);
      As[c4 + 0][row] = a.x;
      As[c4 + 1][row] = a.y;
      As[c4 + 2][row] = a.z;
      As[c4 + 3][row] = a.w;
    }
    {
      int krow = tid >> 4;
      int c4 = (tid & 15) << 2;
      *(float4*)(&Bs[krow][c4]) =
          *(const float4*)(W + (size_t)(k0 + krow) * U_DIM + n0 + c4);
    }
    __syncthreads();
#pragma unroll
    for (int k = 0; k < BK; ++k) {
      float a[8], bb[4];
#pragma unroll
      for (int i = 0; i < 8; ++i) a[i] = As[k][ty * 8 + i];
#pragma unroll
      for (int j = 0; j < 4; ++j) bb[j] = Bs[k][tx * 4 + j];
#pragma unroll
      for (int i = 0; i < 8; ++i)
#pragma unroll
        for (int j = 0; j < 4; ++j) acc[i][j] += a[i] * bb[j];
    }
    __syncthreads();
  }

#pragma unroll
  for (int i = 0; i < 8; ++i) {
    int m = m0 + ty * 8 + i;
    int t = m & (T_DIM - 1);
    float4 o;
#pragma unroll
    for (int j = 0; j < 4; ++j) {
      int n = n0 + tx * 4 + j;
      float v = acc[i][j] + bias[n];
      if (t == 0) v += lb[n];
      if (t == T_DIM - 1) v += rb[n];
      ((float*)&o)[j] = v;
    }
    *(float4*)(out + (size_t)m * U_DIM + n0 + tx * 4) = o;
  }
}

// ---------------------------------------------------------------------------
// aux: copy transitions to output tail, build transposed TrT[u][v] in ws,
// write sequence_lengths.
// ---------------------------------------------------------------------------
__global__ void aux_kernel(const float* __restrict__ tr, float* __restrict__ out_tr,
                           float* __restrict__ trT, float* __restrict__ seqlen)
{
  int idx = blockIdx.x * blockDim.x + threadIdx.x;
  if (idx < U_DIM * U_DIM) {
    float v = tr[idx];
    out_tr[idx] = v;
    int r = idx >> 9;   // v
    int c = idx & 511;  // u
    trT[(size_t)c * U_DIM + r] = v;
  }
  if (idx < B_DIM) seqlen[idx] = (float)T_DIM;
}

// fill the state ring with sentinel, zero done flags (ws is poisoned)
__global__ void init_kernel(unsigned int* __restrict__ ring,
                            unsigned int* __restrict__ done)
{
  int i = blockIdx.x * blockDim.x + threadIdx.x;
  if (i < RING * B_DIM * U_DIM) ring[i] = SENT;
  if (i < B_DIM * NBLK) done[i] = 0u;
}

// ---------------------------------------------------------------------------
// Viterbi forward scan, full-chip: 256 blocks = 8 u-slice blocks x 32 batches.
// blockIdx: b = blk & 31, j = blk >> 5 (u-slice).
// 512 threads: u_local = tid>>3 (64 u's), vseg = tid&7.
// trT slice held in 16 float4 regs per thread (loaded once).
//
// Sync protocol v5 — SENTINEL ring: the poll IS the data.
//  * state words live in ring[t % 8][b][u] (u32 = fp32 bits). Producer
//    (vseg==0 thread of each u) fire-and-forget relaxed-agent stores the
//    value. NO ack wait, NO flag, NO fence in the loop.
//  * consumer thread tid polls ring[(t-1)%8][b][tid] until != SENT; the
//    successful poll already carries the value (removes the flag publish
//    AND the post-detection state load = 2 IF round trips vs v2).
//  * slot recycling: at step t the producer also sentinel-RESETS its word
//    in slot (t+3)%8 (holding step t-5 data, provably consumed). The reset
//    is vmcnt-acked by the NEXT step's __syncthreads, which happens before
//    this block stores data(t+1); any consumer polling slot (t+3) must
//    first have consumed data(t+2) > data(t+1) > that barrier => the reset
//    is at the coherence point before any such poll (no stale-value race).
//    Same-thread same-address ordering covers reset(t) -> data-write(t+3).
//  * first-max tie rule preserved: ascending-v per thread with strict >,
//    index-min tiebreak in the shfl combine (unchanged from v2).
//  * bp nontemporal write-once; ONE agent-release fence per block after the
//    loop, then done-flag; backtracker polls done, acquire-fences, reads bp.
// ---------------------------------------------------------------------------
__global__ __launch_bounds__(512) void scan_kernel(
    const float* __restrict__ pot, const float* __restrict__ trT,
    unsigned int* __restrict__ ring,     // [RING][B][U] fp32 bits / SENT
    unsigned int* __restrict__ done,     // [B][NBLK]
    unsigned short* __restrict__ bp,     // [T-1][B][U]
    float* __restrict__ outv)            // [B][T]
{
  const int blk = blockIdx.x;
  const int b = blk & (B_DIM - 1);
  const int j = blk >> 5;
  const int tid = threadIdx.x;
  const int u_local = tid >> 3;
  const int vseg = tid & 7;
  const int u = j * UB + u_local;

  __shared__ float sh_state[2][U_DIM];
  __shared__ float sh_v[U_DIM];
  __shared__ int sh_i[U_DIM];

  // load this thread's transition slice into registers (once)
  float4 trreg[16];
  const float* trRow = trT + (size_t)u * U_DIM;
#pragma unroll
  for (int m = 0; m < 16; ++m)
    trreg[m] = *(const float4*)(trRow + vseg * 4 + m * 32);

  const float* potb = pot + (size_t)b * T_DIM * U_DIM;
  const size_t bu = (size_t)b * U_DIM;

  for (int t = 1; t < T_DIM; ++t) {
    const int cur = t & 1;
    // independent of peers: issue before the poll so latency hides under it
    float p_u = potb[(size_t)t * U_DIM + u];  // 8-lane broadcast

    float sv;
    if (t > 1) {
      // poll MY state word; the detecting load delivers the value
      const unsigned int* addr =
          &ring[(size_t)((t - 1) & (RING - 1)) * B_DIM * U_DIM + bu + tid];
      unsigned int w;
      do {
        w = AT_LOAD(addr);
      } while (w == SENT);
      sv = __uint_as_float(w);
    } else {
      // t==1: state0 = potentials[:,0] (written by gemm kernel, same stream)
      sv = potb[tid];
    }
    sh_state[cur][tid] = sv;
    __syncthreads();  // the only barrier per step (also vmcnt-acks last
                      // step's reset store — part of the safety argument)

    float best = -3.402823466e38f;
    int bi = 0;
#pragma unroll
    for (int m = 0; m < 16; ++m) {
      float4 st = *(const float4*)(&sh_state[cur][vseg * 4 + m * 32]);
      float4 trv = trreg[m];
      int vbase = vseg * 4 + m * 32;
      float s0 = st.x + trv.x;
      float s1 = st.y + trv.y;
      float s2 = st.z + trv.z;
      float s3 = st.w + trv.w;
      if (s0 > best) { best = s0; bi = vbase; }
      if (s1 > best) { best = s1; bi = vbase + 1; }
      if (s2 > best) { best = s2; bi = vbase + 2; }
      if (s3 > best) { best = s3; bi = vbase + 3; }
    }
    // combine the 8 vseg partials (lanes u_local*8 .. +7), first-max tie rule
#pragma unroll
    for (int d = 1; d < 8; d <<= 1) {
      float ob = __shfl_xor(best, d, 64);
      int oi = __shfl_xor(bi, d, 64);
      if (ob > best || (ob == best && oi < bi)) { best = ob; bi = oi; }
    }
    if (vseg == 0) {
      float ns = best + p_u;
      // recycle: sentinel-reset slot t+3 (holds consumed t-5 data)
      AT_STORE(&ring[(size_t)((t + 3) & (RING - 1)) * B_DIM * U_DIM + bu + u],
               SENT);
      // publish: fire-and-forget; consumers poll until the bits change
      AT_STORE(&ring[(size_t)(t & (RING - 1)) * B_DIM * U_DIM + bu + u],
               __float_as_uint(ns));
      __builtin_nontemporal_store(
          (unsigned short)bi,
          &bp[(size_t)(t - 1) * (B_DIM * U_DIM) + bu + u]);
    }
  }

  // One release fence per block (single wbl2): makes the nt bp stores
  // visible device-wide, then publish "done".
  __syncthreads();  // drains all waves' stores (vmcnt(0) at barrier)
  if (tid == 0) {
    __builtin_amdgcn_fence(__ATOMIC_RELEASE, "agent");
    AT_STORE(&done[b * NBLK + j], 1u);
  }

  // block j==0 of each batch: final argmax + backtrack
  if (j == 0) {
    if (tid < NBLK) {
      while (AT_LOAD(&done[b * NBLK + tid]) == 0u) {}
    }
    __syncthreads();
    // one acquire fence: invalidate possibly-stale L1/L2 lines (bp was
    // written by remote blocks; ws poison from previous launch may linger)
    if (tid == 0) __builtin_amdgcn_fence(__ATOMIC_ACQUIRE, "agent");
    __syncthreads();

    {
      unsigned int w = AT_LOAD(
          &ring[(size_t)((T_DIM - 1) & (RING - 1)) * B_DIM * U_DIM + bu + tid]);
      sh_v[tid] = __uint_as_float(w);
      sh_i[tid] = tid;
    }
    __syncthreads();
    for (int s = 256; s > 0; s >>= 1) {
      if (tid < s) {
        float a = sh_v[tid], c = sh_v[tid + s];
        int ia = sh_i[tid], ic = sh_i[tid + s];
        if (c > a || (c == a && ic < ia)) { sh_v[tid] = c; sh_i[tid] = ic; }
      }
      __syncthreads();
    }
    if (tid == 0) {
      int tag = sh_i[0];
      outv[(size_t)b * T_DIM + (T_DIM - 1)] = (float)tag;
      for (int t = T_DIM - 1; t >= 1; --t) {
        tag = bp[(size_t)(t - 1) * (B_DIM * U_DIM) + bu + tag];
        outv[(size_t)b * T_DIM + (t - 1)] = (float)tag;
      }
    }
  }
}

// ---------------------------------------------------------------------------
extern "C" void kernel_launch(void* const* d_in, const int* in_sizes, int n_in,
                              void* d_out, int out_size, void* d_ws, size_t ws_size,
                              hipStream_t stream)
{
  const float* x    = (const float*)d_in[0];
  const float* W    = (const float*)d_in[1];
  const float* bias = (const float*)d_in[2];
  const float* tr   = (const float*)d_in[3];
  const float* lb   = (const float*)d_in[4];
  const float* rb   = (const float*)d_in[5];

  float* out = (float*)d_out;
  float* out_v   = out;                                      // (B,T) viterbi tags
  float* out_pot = out + (size_t)B_DIM * T_DIM;              // (B,T,U) potentials
  float* out_seq = out_pot + (size_t)B_DIM * T_DIM * U_DIM;  // (B,) seq lengths
  float* out_tr  = out_seq + B_DIM;                          // (U,U) transitions

  // ws layout
  float* trT = (float*)d_ws;                                           // 1 MB
  unsigned int* ring = (unsigned int*)(trT + (size_t)U_DIM * U_DIM);   // 512 KB
  unsigned int* done = ring + (size_t)RING * B_DIM * U_DIM;            // 1 KB
  unsigned short* bp = (unsigned short*)(done + B_DIM * NBLK);         // ~64 MB

  hipLaunchKernelGGL(init_kernel, dim3((RING * B_DIM * U_DIM + 255) / 256),
                     dim3(256), 0, stream, ring, done);
  hipLaunchKernelGGL(aux_kernel, dim3(1024), dim3(256), 0, stream,
                     tr, out_tr, trT, out_seq);
  hipLaunchKernelGGL(gemm_kernel, dim3(M_DIM / BM, U_DIM / BN), dim3(256), 0,
                     stream, x, W, bias, lb, rb, out_pot);
  hipLaunchKernelGGL(scan_kernel, dim3(NBLK * B_DIM), dim3(512), 0, stream,
                     out_pot, trT, ring, done, bp, out_v);
}